// Round 9
// baseline (602.299 us; speedup 1.0000x reference)
//
#include <hip/hip_runtime.h>
#include <hip/hip_bf16.h>

#define NH  12
#define HD  64
#define DIM 768
#define SEQ 2048
#define NB  4
#define MM  (NB*SEQ)   // 8192 rows
#define NKB (SEQ/64)   // 32 key-blocks per head
#define NKB2 (NKB/2)   // 16 per split-K group

typedef short    v8s  __attribute__((ext_vector_type(8)));   // 8 x bf16 (4 VGPRs)
typedef float    v4f  __attribute__((ext_vector_type(4)));
typedef float    v16f __attribute__((ext_vector_type(16)));
typedef unsigned v4u  __attribute__((ext_vector_type(4)));

#if __has_builtin(__builtin_amdgcn_exp2f)
#define EXP2(x) __builtin_amdgcn_exp2f(x)
#else
#define EXP2(x) __builtin_exp2f(x)
#endif

// round-to-nearest-even f32 -> bf16
static __device__ __forceinline__ unsigned short f2b(float f) {
    unsigned int u = __float_as_uint(f);
    return (unsigned short)((u + 0x7FFFu + ((u >> 16) & 1u)) >> 16);
}
// pack two f32 -> (bf16 lo | bf16 hi<<16), round-ties-away: 2 add + 1 perm
static __device__ __forceinline__ unsigned pk2bf(float lo, float hi) {
    return __builtin_amdgcn_perm(__float_as_uint(hi) + 0x8000u,
                                 __float_as_uint(lo) + 0x8000u, 0x07060302u);
}
// async global->LDS DMA, 16B/lane; LDS base wave-uniform, writes base+lane*16
static __device__ __forceinline__ void g2l16(const unsigned short* g, unsigned short* l) {
    __builtin_amdgcn_global_load_lds(
        (const __attribute__((address_space(1))) void*)g,
        (__attribute__((address_space(3))) void*)l, 16, 0, 0);
}

// all five f32->bf16 casts in one flat launch
__global__ void cast_all(const float* __restrict__ x,
                         const float* __restrict__ qw, const float* __restrict__ kw,
                         const float* __restrict__ vw, const float* __restrict__ ow,
                         unsigned short* __restrict__ xb,
                         unsigned short* __restrict__ wqb, unsigned short* __restrict__ wkb,
                         unsigned short* __restrict__ wvb, unsigned short* __restrict__ wob) {
    const int n4x = MM * DIM / 4, n4w = DIM * DIM / 4;
    int i = blockIdx.x * blockDim.x + threadIdx.x;
    if (i >= n4x + 4 * n4w) return;
    const float* in; unsigned short* out; int idx;
    if (i < n4x) { in = x; out = xb; idx = i; }
    else {
        int j = i - n4x;
        int s = j / n4w;
        idx = j - s * n4w;
        in  = (s == 0) ? qw : (s == 1) ? kw : (s == 2) ? vw : ow;
        out = (s == 0) ? wqb : (s == 1) ? wkb : (s == 2) ? wvb : wob;
    }
    float4 v = reinterpret_cast<const float4*>(in)[idx];
    ushort4 o;
    o.x = f2b(v.x); o.y = f2b(v.y); o.z = f2b(v.z); o.w = f2b(v.w);
    reinterpret_cast<ushort4*>(out)[idx] = o;
}

// Merged QKV: grid (MM/128, NH). One block computes Q,K,V for 128 rows x one
// head (64 features). A staged once per kb; 3 weight tiles; 48 MFMA/phase/wave.
__global__ __launch_bounds__(256, 3) void gemm_qkv(
    const unsigned short* __restrict__ A,
    const unsigned short* __restrict__ Wq,
    const unsigned short* __restrict__ Wk,
    const unsigned short* __restrict__ Wv,
    const float* __restrict__ bq,
    const float* __restrict__ bk,
    const float* __restrict__ bvp,
    unsigned short* __restrict__ Qb,
    unsigned short* __restrict__ Kb,
    unsigned short* __restrict__ Vf)
{
    __shared__ __align__(16) unsigned short As[128 * 64];      // 16 KB
    __shared__ __align__(16) unsigned short Bs[3][64 * 64];    // 24 KB

    const int tid  = threadIdx.x;
    const int w    = tid >> 6, lane = tid & 63;
    const int quad = lane >> 4, l16 = lane & 15;
    const int wm   = w & 1,  wn = w >> 1;
    const int lane8 = lane >> 3, sc = lane & 7;
    const int m0   = blockIdx.x * 128;
    const int h    = blockIdx.y;
    const int n0   = h * 64;

    v4f acc[3][4][2];
    #pragma unroll
    for (int s = 0; s < 3; ++s)
        #pragma unroll
        for (int i = 0; i < 4; ++i)
            #pragma unroll
            for (int j = 0; j < 2; ++j)
                acc[s][i][j] = v4f{0.f, 0.f, 0.f, 0.f};

    for (int kb = 0; kb < DIM; kb += 64) {
        __syncthreads();
        #pragma unroll
        for (int t = 0; t < 4; ++t) {
            int r8 = w * 32 + t * 8;
            int r  = r8 + lane8;
            int gch = sc ^ (r & 7);
            g2l16(&A[(size_t)(m0 + r) * DIM + kb + gch * 8], &As[r8 * 64]);
        }
        #pragma unroll
        for (int u = 0; u < 6; ++u) {
            int G = w * 6 + u;               // 0..23: set = G>>3, rowgrp = G&7
            int set = G >> 3, rg = G & 7;
            int row = rg * 8 + lane8;
            int gch = sc ^ (row & 7);
            const unsigned short* Wp = (set == 0) ? Wq : (set == 1) ? Wk : Wv;
            g2l16(&Wp[(size_t)(n0 + row) * DIM + kb + gch * 8], &Bs[set][rg * 8 * 64]);
        }
        __syncthreads();
        #pragma unroll
        for (int kk = 0; kk < 64; kk += 32) {
            int chb = kk >> 3;
            v8s a[4];
            #pragma unroll
            for (int i = 0; i < 4; ++i) {
                int m = wm * 64 + i * 16 + l16;
                a[i] = *reinterpret_cast<const v8s*>(
                    &As[m * 64 + (((chb + quad) ^ (m & 7)) << 3)]);
            }
            #pragma unroll
            for (int s = 0; s < 3; ++s) {
                v8s b[2];
                #pragma unroll
                for (int j = 0; j < 2; ++j) {
                    int n = wn * 32 + j * 16 + l16;
                    b[j] = *reinterpret_cast<const v8s*>(
                        &Bs[s][n * 64 + (((chb + quad) ^ (n & 7)) << 3)]);
                }
                #pragma unroll
                for (int i = 0; i < 4; ++i)
                    #pragma unroll
                    for (int j = 0; j < 2; ++j)
                        acc[s][i][j] = __builtin_amdgcn_mfma_f32_16x16x32_bf16(
                            a[i], b[j], acc[s][i][j], 0, 0, 0);
            }
        }
    }

    // ---- epilogues ----
    #pragma unroll
    for (int s = 0; s < 2; ++s) {
        unsigned short* out = s ? Kb : Qb;
        const float* bias   = s ? bk : bq;
        const float scale   = s ? 1.0f : 0.1803368801f;
        #pragma unroll
        for (int i = 0; i < 4; ++i) {
            #pragma unroll
            for (int j = 0; j < 2; ++j) {
                int hd = wn * 32 + j * 16 + l16;
                float bias_v = bias[n0 + hd];
                #pragma unroll
                for (int r = 0; r < 4; ++r) {
                    int gm = m0 + wm * 64 + i * 16 + quad * 4 + r;
                    int bb = gm >> 11, sq = gm & (SEQ - 1);
                    out[((size_t)(bb * NH + h) * SEQ + sq) * HD + hd] =
                        f2b((acc[s][i][j][r] + bias_v) * scale);
                }
            }
        }
    }
    // V: fragment-native Vf[bh][kbi][hb*4+c][lane][8]
    #pragma unroll
    for (int i = 0; i < 4; ++i) {
        #pragma unroll
        for (int j = 0; j < 2; ++j) {
            int hd = wn * 32 + j * 16 + l16;
            int hb = hd >> 5, l31v = hd & 31;
            float bias_v = bvp[n0 + hd];
            int gm0 = m0 + wm * 64 + i * 16 + quad * 4;
            int bb = gm0 >> 11, sk = gm0 & (SEQ - 1);
            int kbi = sk >> 6;
            int halfv = quad >> 1, j0 = (quad & 1) * 4;
            ushort4 pkv;
            pkv.x = f2b(acc[2][i][j][0] + bias_v);
            pkv.y = f2b(acc[2][i][j][1] + bias_v);
            pkv.z = f2b(acc[2][i][j][2] + bias_v);
            pkv.w = f2b(acc[2][i][j][3] + bias_v);
            size_t frag = ((size_t)(bb * NH + h) * NKB + kbi) * 8 + hb * 4 + i;
            *reinterpret_cast<ushort4*>(
                &Vf[frag * 512 + (halfv * 32 + l31v) * 8 + j0]) = pkv;
        }
    }
}

// Output projection: 128x64 tiles, grid (64, 12) = 768 blocks = 3 WG/CU even.
__global__ __launch_bounds__(256, 3) void gemm_o(
    const unsigned short* __restrict__ A,
    const unsigned short* __restrict__ W,
    const float* __restrict__ bias,
    float* __restrict__ out)
{
    __shared__ __align__(16) unsigned short As[128 * 64];   // 16 KB
    __shared__ __align__(16) unsigned short Bs[64 * 64];    // 8 KB

    const int tid  = threadIdx.x;
    const int w    = tid >> 6, lane = tid & 63;
    const int quad = lane >> 4, l16 = lane & 15;
    const int wm   = w & 1,  wn = w >> 1;
    const int lane8 = lane >> 3, sc = lane & 7;
    const int m0  = blockIdx.x * 128;
    const int n0l = blockIdx.y * 64;

    v4f acc[4][2];
    #pragma unroll
    for (int i = 0; i < 4; ++i)
        #pragma unroll
        for (int j = 0; j < 2; ++j)
            acc[i][j] = v4f{0.f, 0.f, 0.f, 0.f};

    for (int kb = 0; kb < DIM; kb += 64) {
        __syncthreads();
        #pragma unroll
        for (int t = 0; t < 4; ++t) {
            int r8 = w * 32 + t * 8;
            int r  = r8 + lane8;
            int gch = sc ^ (r & 7);
            g2l16(&A[(size_t)(m0 + r) * DIM + kb + gch * 8], &As[r8 * 64]);
        }
        #pragma unroll
        for (int t = 0; t < 2; ++t) {
            int r8 = (w * 2 + t) * 8;
            int r  = r8 + lane8;
            int gch = sc ^ (r & 7);
            g2l16(&W[(size_t)(n0l + r) * DIM + kb + gch * 8], &Bs[r8 * 64]);
        }
        __syncthreads();
        #pragma unroll
        for (int kk = 0; kk < 64; kk += 32) {
            v8s a[4], b[2];
            int chb = kk >> 3;
            #pragma unroll
            for (int i = 0; i < 4; ++i) {
                int m = wm * 64 + i * 16 + l16;
                a[i] = *reinterpret_cast<const v8s*>(
                    &As[m * 64 + (((chb + quad) ^ (m & 7)) << 3)]);
            }
            #pragma unroll
            for (int j = 0; j < 2; ++j) {
                int n = wn * 32 + j * 16 + l16;
                b[j] = *reinterpret_cast<const v8s*>(
                    &Bs[n * 64 + (((chb + quad) ^ (n & 7)) << 3)]);
            }
            #pragma unroll
            for (int i = 0; i < 4; ++i)
                #pragma unroll
                for (int j = 0; j < 2; ++j)
                    acc[i][j] = __builtin_amdgcn_mfma_f32_16x16x32_bf16(a[i], b[j], acc[i][j], 0, 0, 0);
        }
    }

    #pragma unroll
    for (int i = 0; i < 4; ++i) {
        #pragma unroll
        for (int j = 0; j < 2; ++j) {
            int gn = n0l + wn * 32 + j * 16 + l16;
            float bias_v = bias[gn];
            #pragma unroll
            for (int r = 0; r < 4; ++r) {
                int gm = m0 + wm * 64 + i * 16 + quad * 4 + r;
                out[(size_t)gm * DIM + gn] = acc[i][j][r] + bias_v;
            }
        }
    }
}

// Split-K transposed flash attention: 512 threads = 8 waves. Waves 0-3 (grp 0)
// handle keys 0..1023, waves 4-7 (grp 1) keys 1024..2047, same 128 q-rows.
// No running max -> partial (O, li) combine is a pure add through LDS
// (K-dbuf space reused after the loop). 24 waves/CU (was 12).
__global__ __launch_bounds__(512, 6) void attn(
    const unsigned short* __restrict__ Q,
    const unsigned short* __restrict__ K,
    const unsigned short* __restrict__ Vf,
    unsigned short* __restrict__ ctx)
{
    __shared__ __align__(16) unsigned short Ks[2][2][64 * 64];   // [grp][buf], 32 KB
    __shared__ float Ls[4][64];                                  // 1 KB li exchange

    const int tid  = threadIdx.x;
    const int w    = tid >> 6, lane = tid & 63;
    const int grp  = w >> 2, wl = w & 3;
    const int l31  = lane & 31, half = lane >> 5;
    const int lane8 = lane >> 3, sc = lane & 7;
    const int bh   = blockIdx.y;
    const int b    = bh / NH, h = bh % NH;
    const int q0   = blockIdx.x * 128 + wl * 32;
    const int kbase = grp * (SEQ / 2);
    const int kbg   = grp * NKB2;            // first V-fragment tile index

    const unsigned short* Qp = Q  + ((size_t)bh * SEQ + q0) * HD;
    const unsigned short* Kp = K  + (size_t)bh * SEQ * HD;
    const unsigned short* Vh = Vf + (size_t)bh * NKB * 8 * 512 + lane * 8;

    // Q B-frag: B[n=q=l31][k = c*16 + half*8 + j] (pre-scaled by 0.125*log2e)
    v8s bq[4];
    #pragma unroll
    for (int c = 0; c < 4; ++c)
        bq[c] = *reinterpret_cast<const v8s*>(&Qp[l31 * HD + c * 16 + half * 8]);

    // V A-frags for this group's tile 0
    v8s va[2][4];
    #pragma unroll
    for (int hb = 0; hb < 2; ++hb)
        #pragma unroll
        for (int c = 0; c < 4; ++c)
            va[hb][c] = *reinterpret_cast<const v8s*>(
                &Vh[(size_t)kbg * 4096 + (hb * 4 + c) * 512]);

    v16f o0, o1, Z;
    #pragma unroll
    for (int i = 0; i < 16; ++i) { o0[i] = 0.f; o1[i] = 0.f; Z[i] = 0.f; }
    float li = 0.f;

    const int rx = l31 & 7;
    int rdoff[4];
    #pragma unroll
    for (int c = 0; c < 4; ++c)
        rdoff[c] = l31 * 64 + (((c * 2 + half) ^ rx) << 3);

    #define STAGE_K(kb_, buf_)                                                        \
        do {                                                                          \
            _Pragma("unroll")                                                         \
            for (int t = 0; t < 2; ++t) {                                             \
                int r8  = (t * 4 + wl) * 8;                                           \
                int row = r8 + lane8;                                                 \
                int gch = sc ^ (row & 7);                                             \
                g2l16(&Kp[(size_t)((kb_) + row) * HD + gch * 8],                      \
                      &Ks[grp][buf_][r8 * 64]);                                       \
            }                                                                         \
        } while (0)

    STAGE_K(kbase, 0);

    for (int it = 0; it < NKB2; ++it) {
        const int buf = it & 1;
        __syncthreads();                        // drains K-DMA(it)
        if (it + 1 < NKB2) STAGE_K(kbase + (it + 1) * 64, buf ^ 1);

        // S^T[key][q]: s0 = keys 0..31 of tile, s1 = keys 32..63
        v16f s0, s1;
        {
            const unsigned short* Kb_ = &Ks[grp][buf][0];
            v8s ka00 = *reinterpret_cast<const v8s*>(&Kb_[rdoff[0]]);
            v8s ka10 = *reinterpret_cast<const v8s*>(&Kb_[rdoff[0] + 2048]);
            s0 = __builtin_amdgcn_mfma_f32_32x32x16_bf16(ka00, bq[0], Z, 0, 0, 0);
            s1 = __builtin_amdgcn_mfma_f32_32x32x16_bf16(ka10, bq[0], Z, 0, 0, 0);
            #pragma unroll
            for (int c = 1; c < 4; ++c) {
                v8s k0 = *reinterpret_cast<const v8s*>(&Kb_[rdoff[c]]);
                v8s k1 = *reinterpret_cast<const v8s*>(&Kb_[rdoff[c] + 2048]);
                s0 = __builtin_amdgcn_mfma_f32_32x32x16_bf16(k0, bq[c], s0, 0, 0, 0);
                s1 = __builtin_amdgcn_mfma_f32_32x32x16_bf16(k1, bq[c], s1, 0, 0, 0);
            }
        }

        // exp2 + lane-local li + pack key-pairs
        unsigned pk[8][2];
        #pragma unroll
        for (int g = 0; g < 4; ++g) {
            float e0 = EXP2(s0[4*g+0]), e1 = EXP2(s0[4*g+1]);
            float e2 = EXP2(s0[4*g+2]), e3 = EXP2(s0[4*g+3]);
            li += (e0 + e1) + (e2 + e3);
            pk[g][0] = pk2bf(e0, e1);
            pk[g][1] = pk2bf(e2, e3);
            float f0 = EXP2(s1[4*g+0]), f1 = EXP2(s1[4*g+1]);
            float f2 = EXP2(s1[4*g+2]), f3 = EXP2(s1[4*g+3]);
            li += (f0 + f1) + (f2 + f3);
            pk[4+g][0] = pk2bf(f0, f1);
            pk[4+g][1] = pk2bf(f2, f3);
        }

        // P^T B-frags: partner (lane^32) holds the complementary 4-key blocks.
        #pragma unroll
        for (int cp = 0; cp < 4; ++cp) {
            unsigned a0 = pk[2*cp][0],   a1 = pk[2*cp][1];
            unsigned b0 = pk[2*cp+1][0], b1 = pk[2*cp+1][1];
            unsigned u0 = half ? a0 : b0;      // what my partner needs from me
            unsigned u1 = half ? a1 : b1;
            unsigned x0 = __shfl_xor(u0, 32);
            unsigned x1 = __shfl_xor(u1, 32);
            v4u fw;
            fw.x = half ? x0 : a0;
            fw.y = half ? x1 : a1;
            fw.z = half ? b0 : x0;
            fw.w = half ? b1 : x1;
            v8s pf = __builtin_bit_cast(v8s, fw);
            o0 = __builtin_amdgcn_mfma_f32_32x32x16_bf16(va[0][cp], pf, o0, 0, 0, 0);
            o1 = __builtin_amdgcn_mfma_f32_32x32x16_bf16(va[1][cp], pf, o1, 0, 0, 0);
        }

        // prefetch next V tile (coalesced; overlaps next QK^T + softmax)
        if (it + 1 < NKB2) {
            const unsigned short* Vn = Vh + (size_t)(kbg + it + 1) * 4096;
            #pragma unroll
            for (int hb = 0; hb < 2; ++hb)
                #pragma unroll
                for (int c = 0; c < 4; ++c)
                    va[hb][c] = *reinterpret_cast<const v8s*>(&Vn[(hb * 4 + c) * 512]);
        }
    }
    #undef STAGE_K

    // ---- split-K combine through LDS (reuse K space) ----
    float litot = li + __shfl_xor(li, 32);     // this group's 1024-key total for q
    float* Os = reinterpret_cast<float*>(&Ks[0][0][0]);   // 8192 f32 = 32 KB
    __syncthreads();                            // all K reads done
    if (grp == 1) {
        #pragma unroll
        for (int r = 0; r < 16; ++r) {
            Os[(wl * 32 + r)      * 64 + lane] = o0[r];
            Os[(wl * 32 + 16 + r) * 64 + lane] = o1[r];
        }
        if (half == 0) Ls[wl][lane] = litot;    // same value in both halves
    }
    __syncthreads();
    if (grp == 0) {
        float inv = 1.0f / (litot + Ls[wl][l31]);
        #pragma unroll
        for (int r = 0; r < 16; ++r) {
            o0[r] = (o0[r] + Os[(wl * 32 + r)      * 64 + lane]) * inv;
            o1[r] = (o1[r] + Os[(wl * 32 + 16 + r) * 64 + lane]) * inv;
        }
        const int q = q0 + l31;
        size_t base = ((size_t)(b * SEQ + q)) * DIM + h * HD;
        #pragma unroll
        for (int g = 0; g < 4; ++g) {
            int hd0 = 8 * g + 4 * half;
            uint2 u0, u1;
            u0.x = pk2bf(o0[4*g+0], o0[4*g+1]);
            u0.y = pk2bf(o0[4*g+2], o0[4*g+3]);
            u1.x = pk2bf(o1[4*g+0], o1[4*g+1]);
            u1.y = pk2bf(o1[4*g+2], o1[4*g+3]);
            *reinterpret_cast<uint2*>(&ctx[base + hd0])      = u0;
            *reinterpret_cast<uint2*>(&ctx[base + 32 + hd0]) = u1;
        }
    }
}

extern "C" void kernel_launch(void* const* d_in, const int* in_sizes, int n_in,
                              void* d_out, int out_size, void* d_ws, size_t ws_size,
                              hipStream_t stream) {
    const float* x  = (const float*)d_in[0];
    const float* qw = (const float*)d_in[1]; const float* qb = (const float*)d_in[2];
    const float* kw = (const float*)d_in[3]; const float* kb = (const float*)d_in[4];
    const float* vw = (const float*)d_in[5]; const float* vb = (const float*)d_in[6];
    const float* ow = (const float*)d_in[7]; const float* ob = (const float*)d_in[8];
    float* out = (float*)d_out;

    char* ws = (char*)d_ws;
    size_t off = 0;
    auto alloc = [&](size_t bytes) -> unsigned short* {
        unsigned short* p = (unsigned short*)(ws + off);
        off += (bytes + 255) & ~(size_t)255;
        return p;
    };
    const size_t XB = (size_t)MM * DIM * 2;
    const size_t WB = (size_t)DIM * DIM * 2;
    const size_t QB = (size_t)NB * NH * SEQ * HD * 2;

    unsigned short* xb  = alloc(XB);
    unsigned short* wqb = alloc(WB);
    unsigned short* wkb = alloc(WB);
    unsigned short* wvb = alloc(WB);
    unsigned short* wob = alloc(WB);
    unsigned short* Qb  = alloc(QB);
    unsigned short* Kb  = alloc(QB);
    unsigned short* Vfb = alloc(QB);   // fragment-native V
    unsigned short* ctx = alloc(XB);

    const int n4x = MM * DIM / 4, n4w = DIM * DIM / 4;
    const int ncast = n4x + 4 * n4w;
    cast_all<<<(ncast + 255) / 256, 256, 0, stream>>>(
        x, qw, kw, vw, ow, xb, wqb, wkb, wvb, wob);

    gemm_qkv<<<dim3(MM / 128, NH), 256, 0, stream>>>(
        xb, wqb, wkb, wvb, qb, kb, vb, Qb, Kb, Vfb);

    attn<<<dim3(SEQ / 128, NB * NH), 512, 0, stream>>>(Qb, Kb, Vfb, ctx);

    gemm_o<<<dim3(MM / 128, DIM / 64), 256, 0, stream>>>(ctx, wob, ob, out);
}

// Round 10
// 227.619 us; speedup vs baseline: 2.6461x; 2.6461x over previous
//
#include <hip/hip_runtime.h>
#include <hip/hip_bf16.h>

#define NH  12
#define HD  64
#define DIM 768
#define SEQ 2048
#define NB  4
#define MM  (NB*SEQ)   // 8192 rows
#define NKB (SEQ/64)   // 32 key-blocks per head
#define NKB2 (NKB/2)   // 16 per split-K group

typedef short    v8s  __attribute__((ext_vector_type(8)));   // 8 x bf16 (4 VGPRs)
typedef float    v4f  __attribute__((ext_vector_type(4)));
typedef float    v16f __attribute__((ext_vector_type(16)));
typedef unsigned v4u  __attribute__((ext_vector_type(4)));

#if __has_builtin(__builtin_amdgcn_exp2f)
#define EXP2(x) __builtin_amdgcn_exp2f(x)
#else
#define EXP2(x) __builtin_exp2f(x)
#endif

// round-to-nearest-even f32 -> bf16
static __device__ __forceinline__ unsigned short f2b(float f) {
    unsigned int u = __float_as_uint(f);
    return (unsigned short)((u + 0x7FFFu + ((u >> 16) & 1u)) >> 16);
}
// pack two f32 -> (bf16 lo | bf16 hi<<16), round-ties-away: 2 add + 1 perm
static __device__ __forceinline__ unsigned pk2bf(float lo, float hi) {
    return __builtin_amdgcn_perm(__float_as_uint(hi) + 0x8000u,
                                 __float_as_uint(lo) + 0x8000u, 0x07060302u);
}
// async global->LDS DMA, 16B/lane; LDS base wave-uniform, writes base+lane*16
static __device__ __forceinline__ void g2l16(const unsigned short* g, unsigned short* l) {
    __builtin_amdgcn_global_load_lds(
        (const __attribute__((address_space(1))) void*)g,
        (__attribute__((address_space(3))) void*)l, 16, 0, 0);
}

// all five f32->bf16 casts in one flat launch
__global__ void cast_all(const float* __restrict__ x,
                         const float* __restrict__ qw, const float* __restrict__ kw,
                         const float* __restrict__ vw, const float* __restrict__ ow,
                         unsigned short* __restrict__ xb,
                         unsigned short* __restrict__ wqb, unsigned short* __restrict__ wkb,
                         unsigned short* __restrict__ wvb, unsigned short* __restrict__ wob) {
    const int n4x = MM * DIM / 4, n4w = DIM * DIM / 4;
    int i = blockIdx.x * blockDim.x + threadIdx.x;
    if (i >= n4x + 4 * n4w) return;
    const float* in; unsigned short* out; int idx;
    if (i < n4x) { in = x; out = xb; idx = i; }
    else {
        int j = i - n4x;
        int s = j / n4w;
        idx = j - s * n4w;
        in  = (s == 0) ? qw : (s == 1) ? kw : (s == 2) ? vw : ow;
        out = (s == 0) ? wqb : (s == 1) ? wkb : (s == 2) ? wvb : wob;
    }
    float4 v = reinterpret_cast<const float4*>(in)[idx];
    ushort4 o;
    o.x = f2b(v.x); o.y = f2b(v.y); o.z = f2b(v.z); o.w = f2b(v.w);
    reinterpret_cast<ushort4*>(out)[idx] = o;
}

// Merged QKV: grid (MM/128, NH). One block computes Q,K,V for 128 rows x one
// head (64 features). A staged once per kb; 3 weight tiles; 48 MFMA/phase/wave.
__global__ __launch_bounds__(256, 3) void gemm_qkv(
    const unsigned short* __restrict__ A,
    const unsigned short* __restrict__ Wq,
    const unsigned short* __restrict__ Wk,
    const unsigned short* __restrict__ Wv,
    const float* __restrict__ bq,
    const float* __restrict__ bk,
    const float* __restrict__ bvp,
    unsigned short* __restrict__ Qb,
    unsigned short* __restrict__ Kb,
    unsigned short* __restrict__ Vf)
{
    __shared__ __align__(16) unsigned short As[128 * 64];      // 16 KB
    __shared__ __align__(16) unsigned short Bs[3][64 * 64];    // 24 KB

    const int tid  = threadIdx.x;
    const int w    = tid >> 6, lane = tid & 63;
    const int quad = lane >> 4, l16 = lane & 15;
    const int wm   = w & 1,  wn = w >> 1;
    const int lane8 = lane >> 3, sc = lane & 7;
    const int m0   = blockIdx.x * 128;
    const int h    = blockIdx.y;
    const int n0   = h * 64;

    v4f acc[3][4][2];
    #pragma unroll
    for (int s = 0; s < 3; ++s)
        #pragma unroll
        for (int i = 0; i < 4; ++i)
            #pragma unroll
            for (int j = 0; j < 2; ++j)
                acc[s][i][j] = v4f{0.f, 0.f, 0.f, 0.f};

    for (int kb = 0; kb < DIM; kb += 64) {
        __syncthreads();
        #pragma unroll
        for (int t = 0; t < 4; ++t) {
            int r8 = w * 32 + t * 8;
            int r  = r8 + lane8;
            int gch = sc ^ (r & 7);
            g2l16(&A[(size_t)(m0 + r) * DIM + kb + gch * 8], &As[r8 * 64]);
        }
        #pragma unroll
        for (int u = 0; u < 6; ++u) {
            int G = w * 6 + u;               // 0..23: set = G>>3, rowgrp = G&7
            int set = G >> 3, rg = G & 7;
            int row = rg * 8 + lane8;
            int gch = sc ^ (row & 7);
            const unsigned short* Wp = (set == 0) ? Wq : (set == 1) ? Wk : Wv;
            g2l16(&Wp[(size_t)(n0 + row) * DIM + kb + gch * 8], &Bs[set][rg * 8 * 64]);
        }
        __syncthreads();
        #pragma unroll
        for (int kk = 0; kk < 64; kk += 32) {
            int chb = kk >> 3;
            v8s a[4];
            #pragma unroll
            for (int i = 0; i < 4; ++i) {
                int m = wm * 64 + i * 16 + l16;
                a[i] = *reinterpret_cast<const v8s*>(
                    &As[m * 64 + (((chb + quad) ^ (m & 7)) << 3)]);
            }
            #pragma unroll
            for (int s = 0; s < 3; ++s) {
                v8s b[2];
                #pragma unroll
                for (int j = 0; j < 2; ++j) {
                    int n = wn * 32 + j * 16 + l16;
                    b[j] = *reinterpret_cast<const v8s*>(
                        &Bs[s][n * 64 + (((chb + quad) ^ (n & 7)) << 3)]);
                }
                #pragma unroll
                for (int i = 0; i < 4; ++i)
                    #pragma unroll
                    for (int j = 0; j < 2; ++j)
                        acc[s][i][j] = __builtin_amdgcn_mfma_f32_16x16x32_bf16(
                            a[i], b[j], acc[s][i][j], 0, 0, 0);
            }
        }
    }

    // ---- epilogues ----
    #pragma unroll
    for (int s = 0; s < 2; ++s) {
        unsigned short* out = s ? Kb : Qb;
        const float* bias   = s ? bk : bq;
        const float scale   = s ? 1.0f : 0.1803368801f;
        #pragma unroll
        for (int i = 0; i < 4; ++i) {
            #pragma unroll
            for (int j = 0; j < 2; ++j) {
                int hd = wn * 32 + j * 16 + l16;
                float bias_v = bias[n0 + hd];
                #pragma unroll
                for (int r = 0; r < 4; ++r) {
                    int gm = m0 + wm * 64 + i * 16 + quad * 4 + r;
                    int bb = gm >> 11, sq = gm & (SEQ - 1);
                    out[((size_t)(bb * NH + h) * SEQ + sq) * HD + hd] =
                        f2b((acc[s][i][j][r] + bias_v) * scale);
                }
            }
        }
    }
    // V: fragment-native Vf[bh][kbi][hb*4+c][lane][8]
    #pragma unroll
    for (int i = 0; i < 4; ++i) {
        #pragma unroll
        for (int j = 0; j < 2; ++j) {
            int hd = wn * 32 + j * 16 + l16;
            int hb = hd >> 5, l31v = hd & 31;
            float bias_v = bvp[n0 + hd];
            int gm0 = m0 + wm * 64 + i * 16 + quad * 4;
            int bb = gm0 >> 11, sk = gm0 & (SEQ - 1);
            int kbi = sk >> 6;
            int halfv = quad >> 1, j0 = (quad & 1) * 4;
            ushort4 pkv;
            pkv.x = f2b(acc[2][i][j][0] + bias_v);
            pkv.y = f2b(acc[2][i][j][1] + bias_v);
            pkv.z = f2b(acc[2][i][j][2] + bias_v);
            pkv.w = f2b(acc[2][i][j][3] + bias_v);
            size_t frag = ((size_t)(bb * NH + h) * NKB + kbi) * 8 + hb * 4 + i;
            *reinterpret_cast<ushort4*>(
                &Vf[frag * 512 + (halfv * 32 + l31v) * 8 + j0]) = pkv;
        }
    }
}

// Output projection: 128x64 tiles, grid (64, 12) = 768 blocks = 3 WG/CU even.
__global__ __launch_bounds__(256, 3) void gemm_o(
    const unsigned short* __restrict__ A,
    const unsigned short* __restrict__ W,
    const float* __restrict__ bias,
    float* __restrict__ out)
{
    __shared__ __align__(16) unsigned short As[128 * 64];   // 16 KB
    __shared__ __align__(16) unsigned short Bs[64 * 64];    // 8 KB

    const int tid  = threadIdx.x;
    const int w    = tid >> 6, lane = tid & 63;
    const int quad = lane >> 4, l16 = lane & 15;
    const int wm   = w & 1,  wn = w >> 1;
    const int lane8 = lane >> 3, sc = lane & 7;
    const int m0  = blockIdx.x * 128;
    const int n0l = blockIdx.y * 64;

    v4f acc[4][2];
    #pragma unroll
    for (int i = 0; i < 4; ++i)
        #pragma unroll
        for (int j = 0; j < 2; ++j)
            acc[i][j] = v4f{0.f, 0.f, 0.f, 0.f};

    for (int kb = 0; kb < DIM; kb += 64) {
        __syncthreads();
        #pragma unroll
        for (int t = 0; t < 4; ++t) {
            int r8 = w * 32 + t * 8;
            int r  = r8 + lane8;
            int gch = sc ^ (r & 7);
            g2l16(&A[(size_t)(m0 + r) * DIM + kb + gch * 8], &As[r8 * 64]);
        }
        #pragma unroll
        for (int t = 0; t < 2; ++t) {
            int r8 = (w * 2 + t) * 8;
            int r  = r8 + lane8;
            int gch = sc ^ (r & 7);
            g2l16(&W[(size_t)(n0l + r) * DIM + kb + gch * 8], &Bs[r8 * 64]);
        }
        __syncthreads();
        #pragma unroll
        for (int kk = 0; kk < 64; kk += 32) {
            v8s a[4], b[2];
            int chb = kk >> 3;
            #pragma unroll
            for (int i = 0; i < 4; ++i) {
                int m = wm * 64 + i * 16 + l16;
                a[i] = *reinterpret_cast<const v8s*>(
                    &As[m * 64 + (((chb + quad) ^ (m & 7)) << 3)]);
            }
            #pragma unroll
            for (int j = 0; j < 2; ++j) {
                int n = wn * 32 + j * 16 + l16;
                b[j] = *reinterpret_cast<const v8s*>(
                    &Bs[n * 64 + (((chb + quad) ^ (n & 7)) << 3)]);
            }
            #pragma unroll
            for (int i = 0; i < 4; ++i)
                #pragma unroll
                for (int j = 0; j < 2; ++j)
                    acc[i][j] = __builtin_amdgcn_mfma_f32_16x16x32_bf16(a[i], b[j], acc[i][j], 0, 0, 0);
        }
    }

    #pragma unroll
    for (int i = 0; i < 4; ++i) {
        #pragma unroll
        for (int j = 0; j < 2; ++j) {
            int gn = n0l + wn * 32 + j * 16 + l16;
            float bias_v = bias[gn];
            #pragma unroll
            for (int r = 0; r < 4; ++r) {
                int gm = m0 + wm * 64 + i * 16 + quad * 4 + r;
                out[(size_t)gm * DIM + gn] = acc[i][j][r] + bias_v;
            }
        }
    }
}

// Split-K transposed flash attention, 512 threads = 8 waves, NO occupancy cap
// (R9's (512,6) cap forced VGPR=40 + 2GB scratch spill — never cap below need).
// grp0: keys 0..1023, grp1: 1024..2047. Combine = pure add via reused K-LDS.
__global__ __launch_bounds__(512) void attn(
    const unsigned short* __restrict__ Q,
    const unsigned short* __restrict__ K,
    const unsigned short* __restrict__ Vf,
    unsigned short* __restrict__ ctx)
{
    __shared__ __align__(16) unsigned short Ks[2][2][64 * 64];   // [grp][buf], 32 KB
    __shared__ float Ls[4][64];                                  // 1 KB li exchange

    const int tid  = threadIdx.x;
    const int w    = tid >> 6, lane = tid & 63;
    const int grp  = w >> 2, wl = w & 3;
    const int l31  = lane & 31, half = lane >> 5;
    const int lane8 = lane >> 3, sc = lane & 7;
    const int bh   = blockIdx.y;
    const int b    = bh / NH, h = bh % NH;
    const int q0   = blockIdx.x * 128 + wl * 32;
    const int kbase = grp * (SEQ / 2);
    const int kbg   = grp * NKB2;            // first V-fragment tile index

    const unsigned short* Qp = Q  + ((size_t)bh * SEQ + q0) * HD;
    const unsigned short* Kp = K  + (size_t)bh * SEQ * HD;
    const unsigned short* Vh = Vf + (size_t)bh * NKB * 8 * 512 + lane * 8;

    // Q B-frag: B[n=q=l31][k = c*16 + half*8 + j] (pre-scaled by 0.125*log2e)
    v8s bq[4];
    #pragma unroll
    for (int c = 0; c < 4; ++c)
        bq[c] = *reinterpret_cast<const v8s*>(&Qp[l31 * HD + c * 16 + half * 8]);

    // V A-frags for this group's tile 0
    v8s va[2][4];
    #pragma unroll
    for (int hb = 0; hb < 2; ++hb)
        #pragma unroll
        for (int c = 0; c < 4; ++c)
            va[hb][c] = *reinterpret_cast<const v8s*>(
                &Vh[(size_t)kbg * 4096 + (hb * 4 + c) * 512]);

    v16f o0, o1, Z;
    #pragma unroll
    for (int i = 0; i < 16; ++i) { o0[i] = 0.f; o1[i] = 0.f; Z[i] = 0.f; }
    float li = 0.f;

    const int rx = l31 & 7;
    int rdoff[4];
    #pragma unroll
    for (int c = 0; c < 4; ++c)
        rdoff[c] = l31 * 64 + (((c * 2 + half) ^ rx) << 3);

    #define STAGE_K(kb_, buf_)                                                        \
        do {                                                                          \
            _Pragma("unroll")                                                         \
            for (int t = 0; t < 2; ++t) {                                             \
                int r8  = (t * 4 + wl) * 8;                                           \
                int row = r8 + lane8;                                                 \
                int gch = sc ^ (row & 7);                                             \
                g2l16(&Kp[(size_t)((kb_) + row) * HD + gch * 8],                      \
                      &Ks[grp][buf_][r8 * 64]);                                       \
            }                                                                         \
        } while (0)

    STAGE_K(kbase, 0);

    for (int it = 0; it < NKB2; ++it) {
        const int buf = it & 1;
        __syncthreads();                        // drains K-DMA(it)
        if (it + 1 < NKB2) STAGE_K(kbase + (it + 1) * 64, buf ^ 1);

        const unsigned short* Kb_ = &Ks[grp][buf][0];
        unsigned pk[8][2];

        // s0 (keys 0..31): MFMA -> exp -> pack, then release before s1
        {
            v8s ka0 = *reinterpret_cast<const v8s*>(&Kb_[rdoff[0]]);
            v16f s0 = __builtin_amdgcn_mfma_f32_32x32x16_bf16(ka0, bq[0], Z, 0, 0, 0);
            #pragma unroll
            for (int c = 1; c < 4; ++c) {
                v8s k0 = *reinterpret_cast<const v8s*>(&Kb_[rdoff[c]]);
                s0 = __builtin_amdgcn_mfma_f32_32x32x16_bf16(k0, bq[c], s0, 0, 0, 0);
            }
            #pragma unroll
            for (int g = 0; g < 4; ++g) {
                float e0 = EXP2(s0[4*g+0]), e1 = EXP2(s0[4*g+1]);
                float e2 = EXP2(s0[4*g+2]), e3 = EXP2(s0[4*g+3]);
                li += (e0 + e1) + (e2 + e3);
                pk[g][0] = pk2bf(e0, e1);
                pk[g][1] = pk2bf(e2, e3);
            }
        }
        // s1 (keys 32..63)
        {
            v8s ka0 = *reinterpret_cast<const v8s*>(&Kb_[rdoff[0] + 2048]);
            v16f s1 = __builtin_amdgcn_mfma_f32_32x32x16_bf16(ka0, bq[0], Z, 0, 0, 0);
            #pragma unroll
            for (int c = 1; c < 4; ++c) {
                v8s k1 = *reinterpret_cast<const v8s*>(&Kb_[rdoff[c] + 2048]);
                s1 = __builtin_amdgcn_mfma_f32_32x32x16_bf16(k1, bq[c], s1, 0, 0, 0);
            }
            #pragma unroll
            for (int g = 0; g < 4; ++g) {
                float f0 = EXP2(s1[4*g+0]), f1 = EXP2(s1[4*g+1]);
                float f2 = EXP2(s1[4*g+2]), f3 = EXP2(s1[4*g+3]);
                li += (f0 + f1) + (f2 + f3);
                pk[4+g][0] = pk2bf(f0, f1);
                pk[4+g][1] = pk2bf(f2, f3);
            }
        }

        // P^T B-frags: partner (lane^32) holds the complementary 4-key blocks.
        #pragma unroll
        for (int cp = 0; cp < 4; ++cp) {
            unsigned a0 = pk[2*cp][0],   a1 = pk[2*cp][1];
            unsigned b0 = pk[2*cp+1][0], b1 = pk[2*cp+1][1];
            unsigned u0 = half ? a0 : b0;      // what my partner needs from me
            unsigned u1 = half ? a1 : b1;
            unsigned x0 = __shfl_xor(u0, 32);
            unsigned x1 = __shfl_xor(u1, 32);
            v4u fw;
            fw.x = half ? x0 : a0;
            fw.y = half ? x1 : a1;
            fw.z = half ? b0 : x0;
            fw.w = half ? b1 : x1;
            v8s pf = __builtin_bit_cast(v8s, fw);
            o0 = __builtin_amdgcn_mfma_f32_32x32x16_bf16(va[0][cp], pf, o0, 0, 0, 0);
            o1 = __builtin_amdgcn_mfma_f32_32x32x16_bf16(va[1][cp], pf, o1, 0, 0, 0);
        }

        // prefetch next V tile (coalesced; overlaps next QK^T + softmax)
        if (it + 1 < NKB2) {
            const unsigned short* Vn = Vh + (size_t)(kbg + it + 1) * 4096;
            #pragma unroll
            for (int hb = 0; hb < 2; ++hb)
                #pragma unroll
                for (int c = 0; c < 4; ++c)
                    va[hb][c] = *reinterpret_cast<const v8s*>(&Vn[(hb * 4 + c) * 512]);
        }
    }
    #undef STAGE_K

    // ---- split-K combine through LDS (reuse K space) ----
    float litot = li + __shfl_xor(li, 32);     // this group's 1024-key total for q
    float* Os = reinterpret_cast<float*>(&Ks[0][0][0]);   // 8192 f32 = 32 KB
    __syncthreads();                            // all K reads done
    if (grp == 1) {
        #pragma unroll
        for (int r = 0; r < 16; ++r) {
            Os[(wl * 32 + r)      * 64 + lane] = o0[r];
            Os[(wl * 32 + 16 + r) * 64 + lane] = o1[r];
        }
        if (half == 0) Ls[wl][lane] = litot;    // same value in both halves
    }
    __syncthreads();
    if (grp == 0) {
        float inv = 1.0f / (litot + Ls[wl][l31]);
        #pragma unroll
        for (int r = 0; r < 16; ++r) {
            o0[r] = (o0[r] + Os[(wl * 32 + r)      * 64 + lane]) * inv;
            o1[r] = (o1[r] + Os[(wl * 32 + 16 + r) * 64 + lane]) * inv;
        }
        const int q = q0 + l31;
        size_t base = ((size_t)(b * SEQ + q)) * DIM + h * HD;
        #pragma unroll
        for (int g = 0; g < 4; ++g) {
            int hd0 = 8 * g + 4 * half;
            uint2 u0, u1;
            u0.x = pk2bf(o0[4*g+0], o0[4*g+1]);
            u0.y = pk2bf(o0[4*g+2], o0[4*g+3]);
            u1.x = pk2bf(o1[4*g+0], o1[4*g+1]);
            u1.y = pk2bf(o1[4*g+2], o1[4*g+3]);
            *reinterpret_cast<uint2*>(&ctx[base + hd0])      = u0;
            *reinterpret_cast<uint2*>(&ctx[base + 32 + hd0]) = u1;
        }
    }
}

extern "C" void kernel_launch(void* const* d_in, const int* in_sizes, int n_in,
                              void* d_out, int out_size, void* d_ws, size_t ws_size,
                              hipStream_t stream) {
    const float* x  = (const float*)d_in[0];
    const float* qw = (const float*)d_in[1]; const float* qb = (const float*)d_in[2];
    const float* kw = (const float*)d_in[3]; const float* kb = (const float*)d_in[4];
    const float* vw = (const float*)d_in[5]; const float* vb = (const float*)d_in[6];
    const float* ow = (const float*)d_in[7]; const float* ob = (const float*)d_in[8];
    float* out = (float*)d_out;

    char* ws = (char*)d_ws;
    size_t off = 0;
    auto alloc = [&](size_t bytes) -> unsigned short* {
        unsigned short* p = (unsigned short*)(ws + off);
        off += (bytes + 255) & ~(size_t)255;
        return p;
    };
    const size_t XB = (size_t)MM * DIM * 2;
    const size_t WB = (size_t)DIM * DIM * 2;
    const size_t QB = (size_t)NB * NH * SEQ * HD * 2;

    unsigned short* xb  = alloc(XB);
    unsigned short* wqb = alloc(WB);
    unsigned short* wkb = alloc(WB);
    unsigned short* wvb = alloc(WB);
    unsigned short* wob = alloc(WB);
    unsigned short* Qb  = alloc(QB);
    unsigned short* Kb  = alloc(QB);
    unsigned short* Vfb = alloc(QB);   // fragment-native V
    unsigned short* ctx = alloc(XB);

    const int n4x = MM * DIM / 4, n4w = DIM * DIM / 4;
    const int ncast = n4x + 4 * n4w;
    cast_all<<<(ncast + 255) / 256, 256, 0, stream>>>(
        x, qw, kw, vw, ow, xb, wqb, wkb, wvb, wob);

    gemm_qkv<<<dim3(MM / 128, NH), 256, 0, stream>>>(
        xb, wqb, wkb, wvb, qb, kb, vb, Qb, Kb, Vfb);

    attn<<<dim3(SEQ / 128, NB * NH), 512, 0, stream>>>(Qb, Kb, Vfb, ctx);

    gemm_o<<<dim3(MM / 128, DIM / 64), 256, 0, stream>>>(ctx, wob, ob, out);
}